// Round 1
// baseline (507.041 us; speedup 1.0000x reference)
//
#include <hip/hip_runtime.h>
#include <hip/hip_bf16.h>

typedef __attribute__((ext_vector_type(8))) short bf16x8;
typedef __attribute__((ext_vector_type(4))) float f32x4;
typedef unsigned short u16;

#define RMS_EPS 1.1920929e-07f

// Problem dims (fixed)
constexpr int Bb = 2, Ss = 2048, DM = 2048, NH = 16;
constexpr int MROWS = Bb * Ss; // 4096

__device__ __forceinline__ u16 f2bf(float f) {
    __hip_bfloat16 h = __float2bfloat16(f);
    return *reinterpret_cast<u16*>(&h);
}

// ---------------- fp32 -> bf16 convert ----------------
__global__ void cvt_f32_bf16(const float* __restrict__ in, u16* __restrict__ out, int n4) {
    int i = blockIdx.x * 256 + threadIdx.x;
    if (i >= n4) return;
    float4 v = reinterpret_cast<const float4*>(in)[i];
    ushort4 o;
    o.x = f2bf(v.x); o.y = f2bf(v.y); o.z = f2bf(v.z); o.w = f2bf(v.w);
    reinterpret_cast<ushort4*>(out)[i] = o;
}

// ---------------- GEMM: C(M,N) = A(M,K) * Bt(N,K)^T + bias ----------------
// 128x128 tile, BK=32, 256 threads (4 waves, each 64x64)
template <typename OutT>
__global__ __launch_bounds__(256) void gemm_bt(
    const u16* __restrict__ A, const u16* __restrict__ Bt,
    const float* __restrict__ bias, OutT* __restrict__ C,
    int M, int N, int K)
{
    __shared__ alignas(16) u16 sA[128 * 32];
    __shared__ alignas(16) u16 sB[128 * 32];
    const int tid = threadIdx.x;
    const int lane = tid & 63;
    const int w = tid >> 6;
    const int wr = w >> 1, wc = w & 1;
    const int l16 = lane & 15, lq = lane >> 4;
    const int tileM = blockIdx.y * 128;
    const int tileN = blockIdx.x * 128;

    f32x4 acc[4][4];
#pragma unroll
    for (int m = 0; m < 4; m++)
#pragma unroll
        for (int n = 0; n < 4; n++)
#pragma unroll
            for (int r = 0; r < 4; r++) acc[m][n][r] = 0.f;

    // staging: chunk c = tid (rows 0..63) and tid+256 (rows 64..127); row=c>>2, blk=c&3
    const int r0 = tid >> 2, b0 = tid & 3;
    const u16* gA0 = A + (size_t)(tileM + r0) * K + b0 * 8;
    const u16* gA1 = A + (size_t)(tileM + r0 + 64) * K + b0 * 8;
    const u16* gB0 = Bt + (size_t)(tileN + r0) * K + b0 * 8;
    const u16* gB1 = Bt + (size_t)(tileN + r0 + 64) * K + b0 * 8;
    // LDS u16 index: row*32 + (blk ^ ((row>>1)&3))*8 ; note ((r0+64)>>1)&3 == (r0>>1)&3
    const int wOff0 = r0 * 32 + ((b0 ^ ((r0 >> 1) & 3)) << 3);
    const int wOff1 = wOff0 + 64 * 32;

    int aoff[4], boff[4];
#pragma unroll
    for (int m = 0; m < 4; m++) {
        int row = wr * 64 + m * 16 + l16;
        aoff[m] = row * 32 + ((lq ^ ((row >> 1) & 3)) << 3);
    }
#pragma unroll
    for (int n = 0; n < 4; n++) {
        int row = wc * 64 + n * 16 + l16;
        boff[n] = row * 32 + ((lq ^ ((row >> 1) & 3)) << 3);
    }

    const int nk = K >> 5;
    for (int kk = 0; kk < nk; ++kk) {
        bf16x8 va0 = *(const bf16x8*)gA0;
        bf16x8 va1 = *(const bf16x8*)gA1;
        bf16x8 vb0 = *(const bf16x8*)gB0;
        bf16x8 vb1 = *(const bf16x8*)gB1;
        gA0 += 32; gA1 += 32; gB0 += 32; gB1 += 32;
        __syncthreads();
        *(bf16x8*)&sA[wOff0] = va0;
        *(bf16x8*)&sA[wOff1] = va1;
        *(bf16x8*)&sB[wOff0] = vb0;
        *(bf16x8*)&sB[wOff1] = vb1;
        __syncthreads();
        bf16x8 af[4], bfr[4];
#pragma unroll
        for (int m = 0; m < 4; m++) af[m] = *(const bf16x8*)&sA[aoff[m]];
#pragma unroll
        for (int n = 0; n < 4; n++) bfr[n] = *(const bf16x8*)&sB[boff[n]];
#pragma unroll
        for (int m = 0; m < 4; m++)
#pragma unroll
            for (int n = 0; n < 4; n++)
                acc[m][n] = __builtin_amdgcn_mfma_f32_16x16x32_bf16(af[m], bfr[n], acc[m][n], 0, 0, 0);
    }

#pragma unroll
    for (int n = 0; n < 4; n++) {
        int col = tileN + wc * 64 + n * 16 + l16;
        float bv = bias ? bias[col] : 0.f;
#pragma unroll
        for (int m = 0; m < 4; m++) {
            int rowb = tileM + wr * 64 + m * 16 + (lq << 2);
#pragma unroll
            for (int r = 0; r < 4; r++) {
                float v = acc[m][n][r] + bv;
                if constexpr (sizeof(OutT) == 2)
                    C[(size_t)(rowb + r) * N + col] = (OutT)f2bf(v);
                else
                    C[(size_t)(rowb + r) * N + col] = (OutT)v;
            }
        }
    }
}

// ---------------- RMS norm (row-wise), fp32 in -> bf16 out ----------------
template <int C>
__global__ __launch_bounds__(256) void rmsnorm_bf16(
    const float* __restrict__ in, const float* __restrict__ wgt, u16* __restrict__ out)
{
    const int row = blockIdx.x;
    const int tid = threadIdx.x;
    constexpr int PER = C / 256;
    const float* p = in + (size_t)row * C;
    float v[PER];
    float ss = 0.f;
#pragma unroll
    for (int i = 0; i < PER; i++) { v[i] = p[tid + i * 256]; ss += v[i] * v[i]; }
#pragma unroll
    for (int o = 32; o; o >>= 1) ss += __shfl_xor(ss, o, 64);
    __shared__ float red[4];
    if ((tid & 63) == 0) red[tid >> 6] = ss;
    __syncthreads();
    float tot = red[0] + red[1] + red[2] + red[3];
    float inv = rsqrtf(tot / (float)C + RMS_EPS);
    u16* q = out + (size_t)row * C;
#pragma unroll
    for (int i = 0; i < PER; i++) {
        int c = tid + i * 256;
        q[c] = f2bf(v[i] * inv * wgt[c]);
    }
}

// ---------------- causal flash attention ----------------
// grid: (S/64, B*NH); block 256 (4 waves x 16 q-rows). D=128, KT=64.
__global__ __launch_bounds__(256) void mla_attn(
    const u16* __restrict__ qbuf,   // (4096, 2048) head-major h*128
    const u16* __restrict__ kvbuf,  // (4096, 3072) per head 192: knope(64) v(128)
    const u16* __restrict__ krbuf,  // (4096, 1024) per head 64
    u16* __restrict__ obuf)         // (4096, 2048)
{
    const int qt = blockIdx.x;
    const int bh = blockIdx.y;
    const int b = bh >> 4, h = bh & 15;
    const int tid = threadIdx.x, lane = tid & 63, w = tid >> 6;
    const int l16 = lane & 15, lq = lane >> 4;

    __shared__ alignas(16) u16 sK[64 * 128];
    __shared__ alignas(16) u16 sVt[128 * 64];
    __shared__ alignas(16) u16 sP[4][16 * 64];

    const int rowbase = b * Ss;
    const int q0 = qt * 64;

    bf16x8 qf[4];
    {
        const u16* qp = qbuf + (size_t)(rowbase + q0 + w * 16 + l16) * 2048 + h * 128 + lq * 8;
#pragma unroll
        for (int c = 0; c < 4; c++) qf[c] = *(const bf16x8*)(qp + c * 32);
    }
    float mi[4], li[4];
    f32x4 o[8];
#pragma unroll
    for (int r = 0; r < 4; r++) { mi[r] = -1e30f; li[r] = 0.f; }
#pragma unroll
    for (int d = 0; d < 8; d++)
#pragma unroll
        for (int r = 0; r < 4; r++) o[d][r] = 0.f;

    const int sr = tid >> 2;          // key row 0..63
    const int sc = (tid & 3) * 32;    // col segment 0/32/64/96

    for (int kt = 0; kt <= qt; ++kt) {
        __syncthreads();
        {
            const int krow = rowbase + kt * 64 + sr;
            const u16* src = (sc < 64)
                ? kvbuf + (size_t)krow * 3072 + h * 192 + sc
                : krbuf + (size_t)krow * 1024 + h * 64 + (sc - 64);
#pragma unroll
            for (int j = 0; j < 4; j++) {
                int byteoff = sr * 256 + (sc + j * 8) * 2;
                *(bf16x8*)((char*)sK + (byteoff ^ ((sr & 7) << 4))) = *(const bf16x8*)(src + j * 8);
            }
            const u16* vs = kvbuf + (size_t)krow * 3072 + h * 192 + 64 + sc;
            bf16x8 vv[4];
#pragma unroll
            for (int jj = 0; jj < 4; jj++) vv[jj] = *(const bf16x8*)(vs + jj * 8);
#pragma unroll
            for (int jj = 0; jj < 4; jj++)
#pragma unroll
                for (int e = 0; e < 8; e++) {
                    int d = sc + jj * 8 + e;
                    int byteoff = d * 128 + sr * 2;
                    *(u16*)((char*)sVt + (byteoff ^ ((d & 7) << 4))) = (u16)vv[jj][e];
                }
        }
        __syncthreads();

        // QK^T: 16 q-rows x 64 keys per wave
        f32x4 scf[4];
#pragma unroll
        for (int n = 0; n < 4; n++) {
#pragma unroll
            for (int r = 0; r < 4; r++) scf[n][r] = 0.f;
#pragma unroll
            for (int c = 0; c < 4; c++) {
                int row = n * 16 + l16;
                int byteoff = row * 256 + (c * 32 + lq * 8) * 2;
                bf16x8 kf = *(const bf16x8*)((char*)sK + (byteoff ^ ((row & 7) << 4)));
                scf[n] = __builtin_amdgcn_mfma_f32_16x16x32_bf16(qf[c], kf, scf[n], 0, 0, 0);
            }
        }
        const float scale = 0.08838834764831845f;
        float mnew[4];
#pragma unroll
        for (int r = 0; r < 4; r++) mnew[r] = mi[r];
        const int qg_base = q0 + w * 16 + lq * 4;
#pragma unroll
        for (int n = 0; n < 4; n++) {
            int kg = kt * 64 + n * 16 + l16;
#pragma unroll
            for (int r = 0; r < 4; r++) {
                float s = scf[n][r] * scale;
                s = (kg <= qg_base + r) ? s : -1e30f;
                scf[n][r] = s;
                mnew[r] = fmaxf(mnew[r], s);
            }
        }
#pragma unroll
        for (int off = 8; off; off >>= 1)
#pragma unroll
            for (int r = 0; r < 4; r++) mnew[r] = fmaxf(mnew[r], __shfl_xor(mnew[r], off, 64));
        float rs[4] = {0.f, 0.f, 0.f, 0.f};
#pragma unroll
        for (int n = 0; n < 4; n++)
#pragma unroll
            for (int r = 0; r < 4; r++) {
                float p = __expf(scf[n][r] - mnew[r]);
                scf[n][r] = p;
                rs[r] += p;
            }
#pragma unroll
        for (int off = 8; off; off >>= 1)
#pragma unroll
            for (int r = 0; r < 4; r++) rs[r] += __shfl_xor(rs[r], off, 64);
#pragma unroll
        for (int r = 0; r < 4; r++) {
            float f = __expf(mi[r] - mnew[r]);
            li[r] = li[r] * f + rs[r];
            mi[r] = mnew[r];
#pragma unroll
            for (int d = 0; d < 8; d++) o[d][r] *= f;
        }
        // P -> LDS (D-layout -> A-layout bounce)
#pragma unroll
        for (int n = 0; n < 4; n++)
#pragma unroll
            for (int r = 0; r < 4; r++) {
                int row = lq * 4 + r;
                int byteoff = row * 128 + (n * 16 + l16) * 2;
                *(u16*)((char*)sP[w] + (byteoff ^ ((row & 7) << 4))) = f2bf(scf[n][r]);
            }
        __syncthreads();
        // PV
#pragma unroll
        for (int c = 0; c < 2; c++) {
            int pbyte = l16 * 128 + (c * 32 + lq * 8) * 2;
            bf16x8 pf = *(const bf16x8*)((char*)sP[w] + (pbyte ^ ((l16 & 7) << 4)));
#pragma unroll
            for (int d = 0; d < 8; d++) {
                int vrow = d * 16 + l16;
                int vbyte = vrow * 128 + (c * 32 + lq * 8) * 2;
                bf16x8 vf = *(const bf16x8*)((char*)sVt + (vbyte ^ ((vrow & 7) << 4)));
                o[d] = __builtin_amdgcn_mfma_f32_16x16x32_bf16(pf, vf, o[d], 0, 0, 0);
            }
        }
    }
    // epilogue
    u16* op = obuf + (size_t)(rowbase + q0 + w * 16) * 2048 + h * 128;
#pragma unroll
    for (int r = 0; r < 4; r++) {
        float invl = 1.f / li[r];
        int row = lq * 4 + r;
#pragma unroll
        for (int d = 0; d < 8; d++)
            op[(size_t)row * 2048 + d * 16 + l16] = f2bf(o[d][r] * invl);
    }
}

// ---------------- launch ----------------
extern "C" void kernel_launch(void* const* d_in, const int* in_sizes, int n_in,
                              void* d_out, int out_size, void* d_ws, size_t ws_size,
                              hipStream_t stream) {
    const float* x        = (const float*)d_in[0];
    const float* q_down_w = (const float*)d_in[1];
    const float* q_down_b = (const float*)d_in[2];
    const float* q_norm_w = (const float*)d_in[3];
    const float* q_up_w   = (const float*)d_in[4];
    const float* q_up_b   = (const float*)d_in[5];
    const float* kv_down_w= (const float*)d_in[6];
    const float* kv_down_b= (const float*)d_in[7];
    const float* kv_norm_w= (const float*)d_in[8];
    const float* kv_up_w  = (const float*)d_in[9];
    const float* kv_up_b  = (const float*)d_in[10];
    const float* k_rope_w = (const float*)d_in[11];
    const float* k_rope_b = (const float*)d_in[12];
    const float* out_w    = (const float*)d_in[13];
    const float* out_b    = (const float*)d_in[14];

    char* ws = (char*)d_ws;
    u16* xbf    = (u16*)(ws + 0);
    u16* qdw    = (u16*)(ws + 16777216);
    u16* quw    = (u16*)(ws + 20971520);
    u16* kvdw   = (u16*)(ws + 25165824);
    u16* kvuw   = (u16*)(ws + 27262976);
    u16* krw    = (u16*)(ws + 30408704);
    u16* outw   = (u16*)(ws + 34603008);
    float* cqpre  = (float*)(ws + 42991616); // 16.8MB, later reused as attn buf
    float* ckvpre = (float*)(ws + 59768832); // 8.4MB, later reused as krope buf
    u16* cq     = (u16*)(ws + 68157440);
    u16* ckv    = (u16*)(ws + 76546048);
    u16* qbuf   = (u16*)(ws + 80740352);
    u16* kvbuf  = (u16*)(ws + 97517568);
    u16* krbuf  = (u16*)(ws + 59768832);  // alias ckvpre
    u16* attnbuf= (u16*)(ws + 42991616);  // alias cqpre

    auto cvt = [&](const float* src, u16* dst, int n) {
        int n4 = n / 4;
        cvt_f32_bf16<<<(n4 + 255) / 256, 256, 0, stream>>>(src, dst, n4);
    };
    cvt(x,         xbf,  MROWS * DM);
    cvt(q_down_w,  qdw,  1024 * 2048);
    cvt(q_up_w,    quw,  2048 * 1024);
    cvt(kv_down_w, kvdw, 512 * 2048);
    cvt(kv_up_w,   kvuw, 3072 * 512);
    cvt(k_rope_w,  krw,  1024 * 2048);
    cvt(out_w,     outw, 2048 * 2048);

    // q path
    gemm_bt<float><<<dim3(8, 32), 256, 0, stream>>>(xbf, qdw, q_down_b, cqpre, MROWS, 1024, 2048);
    rmsnorm_bf16<1024><<<MROWS, 256, 0, stream>>>(cqpre, q_norm_w, cq);
    gemm_bt<u16><<<dim3(16, 32), 256, 0, stream>>>(cq, quw, q_up_b, qbuf, MROWS, 2048, 1024);
    // kv path
    gemm_bt<float><<<dim3(4, 32), 256, 0, stream>>>(xbf, kvdw, kv_down_b, ckvpre, MROWS, 512, 2048);
    rmsnorm_bf16<512><<<MROWS, 256, 0, stream>>>(ckvpre, kv_norm_w, ckv);
    gemm_bt<u16><<<dim3(24, 32), 256, 0, stream>>>(ckv, kvuw, kv_up_b, kvbuf, MROWS, 3072, 512);
    // k_rope (after rmsnorm<512> since krbuf aliases ckvpre)
    gemm_bt<u16><<<dim3(8, 32), 256, 0, stream>>>(xbf, krw, k_rope_b, krbuf, MROWS, 1024, 2048);
    // attention
    mla_attn<<<dim3(Ss / 64, Bb * NH), 256, 0, stream>>>(qbuf, kvbuf, krbuf, attnbuf);
    // output projection
    gemm_bt<float><<<dim3(16, 32), 256, 0, stream>>>(attnbuf, outw, out_b, (float*)d_out, MROWS, 2048, 2048);
}

// Round 2
// 395.111 us; speedup vs baseline: 1.2833x; 1.2833x over previous
//
#include <hip/hip_runtime.h>
#include <hip/hip_bf16.h>

typedef __attribute__((ext_vector_type(8))) short bf16x8;
typedef __attribute__((ext_vector_type(4))) float f32x4;
typedef unsigned short u16;

#define RMS_EPS 1.1920929e-07f

constexpr int Bb = 2, Ss = 2048, DM = 2048, NH = 16;
constexpr int MROWS = Bb * Ss; // 4096

__device__ __forceinline__ u16 f2bf(float f) {
    __hip_bfloat16 h = __float2bfloat16(f);
    return *reinterpret_cast<u16*>(&h);
}

__device__ __forceinline__ void gload16(const void* g, void* l) {
    __builtin_amdgcn_global_load_lds(
        (const __attribute__((address_space(1))) unsigned int*)g,
        (__attribute__((address_space(3))) unsigned int*)l, 16, 0, 0);
}

// ---------------- fp32 -> bf16 convert ----------------
__global__ void cvt_f32_bf16(const float* __restrict__ in, u16* __restrict__ out, int n4) {
    int i = blockIdx.x * 256 + threadIdx.x;
    if (i >= n4) return;
    float4 v = reinterpret_cast<const float4*>(in)[i];
    ushort4 o;
    o.x = f2bf(v.x); o.y = f2bf(v.y); o.z = f2bf(v.z); o.w = f2bf(v.w);
    reinterpret_cast<ushort4*>(out)[i] = o;
}

__global__ void build_bcat(const float* __restrict__ qb, const float* __restrict__ kvb,
                           const float* __restrict__ krb, float* __restrict__ bcat) {
    int i = blockIdx.x * 256 + threadIdx.x;
    if (i < 1024) bcat[i] = qb[i];
    else if (i < 1536) bcat[i] = kvb[i - 1024];
    else if (i < 2560) bcat[i] = krb[i - 1536];
}

// ---------------- GEMM: C(M,N) = A(M,K) * Bt(N,K)^T + bias ----------------
// 128x128 tile, BK=32, 256 threads (4 waves); global_load_lds staging (m97)
template <typename OutT>
__global__ __launch_bounds__(256) void gemm_bt(
    const u16* __restrict__ A, const u16* __restrict__ Bt,
    const float* __restrict__ bias, OutT* __restrict__ C,
    int M, int N, int K)
{
    __shared__ alignas(16) u16 sA[128 * 32];
    __shared__ alignas(16) u16 sB[128 * 32];
    const int tid = threadIdx.x;
    const int lane = tid & 63;
    const int w = tid >> 6;
    const int wr = w >> 1, wc = w & 1;
    const int l16 = lane & 15, lq = lane >> 4;
    const int tileM = blockIdx.y * 128;
    const int tileN = blockIdx.x * 128;

    f32x4 acc[4][4];
#pragma unroll
    for (int m = 0; m < 4; m++)
#pragma unroll
        for (int n = 0; n < 4; n++)
#pragma unroll
            for (int r = 0; r < 4; r++) acc[m][n][r] = 0.f;

    // staging: lane l of wave w -> LDS bytes w*1024 + l*16 (+ 4096 for 2nd call)
    // row = w*16 + (l>>2) (+64), col = (l&3)*8
    const int srow = w * 16 + (lane >> 2);
    const int scol = (lane & 3) * 8;
    const u16* gA0 = A + (size_t)(tileM + srow) * K + scol;
    const u16* gA1 = A + (size_t)(tileM + srow + 64) * K + scol;
    const u16* gB0 = Bt + (size_t)(tileN + srow) * K + scol;
    const u16* gB1 = Bt + (size_t)(tileN + srow + 64) * K + scol;
    u16* lA0 = sA + w * 512;
    u16* lA1 = sA + 2048 + w * 512;
    u16* lB0 = sB + w * 512;
    u16* lB1 = sB + 2048 + w * 512;

    int aoff[4], boff[4];
#pragma unroll
    for (int m = 0; m < 4; m++) aoff[m] = (wr * 64 + m * 16 + l16) * 32 + lq * 8;
#pragma unroll
    for (int n = 0; n < 4; n++) boff[n] = (wc * 64 + n * 16 + l16) * 32 + lq * 8;

    const int nk = K >> 5;
    for (int kk = 0; kk < nk; ++kk) {
        __syncthreads();
        gload16(gA0, lA0);
        gload16(gA1, lA1);
        gload16(gB0, lB0);
        gload16(gB1, lB1);
        gA0 += 32; gA1 += 32; gB0 += 32; gB1 += 32;
        __syncthreads();
        bf16x8 af[4], bfr[4];
#pragma unroll
        for (int m = 0; m < 4; m++) af[m] = *(const bf16x8*)&sA[aoff[m]];
#pragma unroll
        for (int n = 0; n < 4; n++) bfr[n] = *(const bf16x8*)&sB[boff[n]];
        __builtin_amdgcn_s_setprio(1);
#pragma unroll
        for (int m = 0; m < 4; m++)
#pragma unroll
            for (int n = 0; n < 4; n++)
                acc[m][n] = __builtin_amdgcn_mfma_f32_16x16x32_bf16(af[m], bfr[n], acc[m][n], 0, 0, 0);
        __builtin_amdgcn_s_setprio(0);
    }

#pragma unroll
    for (int n = 0; n < 4; n++) {
        int col = tileN + wc * 64 + n * 16 + l16;
        float bv = bias ? bias[col] : 0.f;
#pragma unroll
        for (int m = 0; m < 4; m++) {
            int rowb = tileM + wr * 64 + m * 16 + (lq << 2);
#pragma unroll
            for (int r = 0; r < 4; r++) {
                float v = acc[m][n][r] + bv;
                if constexpr (sizeof(OutT) == 2)
                    C[(size_t)(rowb + r) * N + col] = (OutT)f2bf(v);
                else
                    C[(size_t)(rowb + r) * N + col] = (OutT)v;
            }
        }
    }
}

// ---------------- fused down-proj GEMM: N=2560 (1024 q | 512 kv | 1024 rope) ----
__global__ __launch_bounds__(256) void gemm_down(
    const u16* __restrict__ A, const u16* __restrict__ Bt,
    const float* __restrict__ bcat, float* __restrict__ dcat,
    u16* __restrict__ krbuf)
{
    constexpr int K = 2048;
    __shared__ alignas(16) u16 sA[128 * 32];
    __shared__ alignas(16) u16 sB[128 * 32];
    const int tid = threadIdx.x;
    const int lane = tid & 63;
    const int w = tid >> 6;
    const int wr = w >> 1, wc = w & 1;
    const int l16 = lane & 15, lq = lane >> 4;
    const int tileM = blockIdx.y * 128;
    const int tileN = blockIdx.x * 128;

    f32x4 acc[4][4];
#pragma unroll
    for (int m = 0; m < 4; m++)
#pragma unroll
        for (int n = 0; n < 4; n++)
#pragma unroll
            for (int r = 0; r < 4; r++) acc[m][n][r] = 0.f;

    const int srow = w * 16 + (lane >> 2);
    const int scol = (lane & 3) * 8;
    const u16* gA0 = A + (size_t)(tileM + srow) * K + scol;
    const u16* gA1 = A + (size_t)(tileM + srow + 64) * K + scol;
    const u16* gB0 = Bt + (size_t)(tileN + srow) * K + scol;
    const u16* gB1 = Bt + (size_t)(tileN + srow + 64) * K + scol;
    u16* lA0 = sA + w * 512;
    u16* lA1 = sA + 2048 + w * 512;
    u16* lB0 = sB + w * 512;
    u16* lB1 = sB + 2048 + w * 512;

    int aoff[4], boff[4];
#pragma unroll
    for (int m = 0; m < 4; m++) aoff[m] = (wr * 64 + m * 16 + l16) * 32 + lq * 8;
#pragma unroll
    for (int n = 0; n < 4; n++) boff[n] = (wc * 64 + n * 16 + l16) * 32 + lq * 8;

    const int nk = K >> 5;
    for (int kk = 0; kk < nk; ++kk) {
        __syncthreads();
        gload16(gA0, lA0);
        gload16(gA1, lA1);
        gload16(gB0, lB0);
        gload16(gB1, lB1);
        gA0 += 32; gA1 += 32; gB0 += 32; gB1 += 32;
        __syncthreads();
        bf16x8 af[4], bfr[4];
#pragma unroll
        for (int m = 0; m < 4; m++) af[m] = *(const bf16x8*)&sA[aoff[m]];
#pragma unroll
        for (int n = 0; n < 4; n++) bfr[n] = *(const bf16x8*)&sB[boff[n]];
        __builtin_amdgcn_s_setprio(1);
#pragma unroll
        for (int m = 0; m < 4; m++)
#pragma unroll
            for (int n = 0; n < 4; n++)
                acc[m][n] = __builtin_amdgcn_mfma_f32_16x16x32_bf16(af[m], bfr[n], acc[m][n], 0, 0, 0);
        __builtin_amdgcn_s_setprio(0);
    }

    const bool isrope = (tileN >= 1536);
#pragma unroll
    for (int n = 0; n < 4; n++) {
        int col = tileN + wc * 64 + n * 16 + l16;
        float bv = bcat[col];
#pragma unroll
        for (int m = 0; m < 4; m++) {
            int rowb = tileM + wr * 64 + m * 16 + (lq << 2);
#pragma unroll
            for (int r = 0; r < 4; r++) {
                float v = acc[m][n][r] + bv;
                if (!isrope) dcat[(size_t)(rowb + r) * 1536 + col] = v;
                else         krbuf[(size_t)(rowb + r) * 1024 + (col - 1536)] = f2bf(v);
            }
        }
    }
}

// ---------------- RMS norm (row-wise, strided in), fp32 in -> bf16 out --------
template <int C>
__global__ __launch_bounds__(256) void rmsnorm_bf16(
    const float* __restrict__ in, int istride, const float* __restrict__ wgt, u16* __restrict__ out)
{
    const int row = blockIdx.x;
    const int tid = threadIdx.x;
    constexpr int PER = C / 256;
    const float* p = in + (size_t)row * istride;
    float v[PER];
    float ss = 0.f;
#pragma unroll
    for (int i = 0; i < PER; i++) { v[i] = p[tid + i * 256]; ss += v[i] * v[i]; }
#pragma unroll
    for (int o = 32; o; o >>= 1) ss += __shfl_xor(ss, o, 64);
    __shared__ float red[4];
    if ((tid & 63) == 0) red[tid >> 6] = ss;
    __syncthreads();
    float tot = red[0] + red[1] + red[2] + red[3];
    float inv = rsqrtf(tot / (float)C + RMS_EPS);
    u16* q = out + (size_t)row * C;
#pragma unroll
    for (int i = 0; i < PER; i++) {
        int c = tid + i * 256;
        q[c] = f2bf(v[i] * inv * wgt[c]);
    }
}

// ---------------- V transpose: kvbuf[token][h*192+64+d] -> vT[(h*128+d)*4096+token]
__global__ __launch_bounds__(256) void transpose_v(
    const u16* __restrict__ kvbuf, u16* __restrict__ vT)
{
    __shared__ alignas(16) u16 tile[64][72];
    const int tid = threadIdx.x;
    const int t0 = blockIdx.x * 64;
    const int h = blockIdx.y >> 1, dh = blockIdx.y & 1;
    const int trow = tid >> 2, c8 = (tid & 3) * 8;
    const u16* src = kvbuf + (size_t)(t0 + trow) * 3072 + h * 192 + 64 + dh * 64 + c8;
    *(bf16x8*)&tile[trow][c8]      = *(const bf16x8*)src;
    *(bf16x8*)&tile[trow][c8 + 32] = *(const bf16x8*)(src + 32);
    __syncthreads();
    const int drow = tid >> 2, tc8 = (tid & 3) * 8;
    bf16x8 a, b2;
#pragma unroll
    for (int j = 0; j < 8; j++) {
        a[j]  = (short)tile[tc8 + j][drow];
        b2[j] = (short)tile[tc8 + 32 + j][drow];
    }
    u16* dst = vT + (size_t)(h * 128 + dh * 64 + drow) * MROWS + t0 + tc8;
    *(bf16x8*)dst = a;
    *(bf16x8*)(dst + 32) = b2;
}

// ---------------- causal flash attention ----------------
// grid: (S/64, B*NH); block 256 (4 waves x 16 q-rows). D=128, KT=64.
__global__ __launch_bounds__(256) void mla_attn(
    const u16* __restrict__ qbuf,   // (4096, 2048) head-major h*128
    const u16* __restrict__ kvbuf,  // (4096, 3072) per head 192: knope(64) v(128)
    const u16* __restrict__ krbuf,  // (4096, 1024) per head 64
    const u16* __restrict__ vT,     // (h*128+d, 4096 tokens)
    u16* __restrict__ obuf)         // (4096, 2048)
{
    const int qt = blockIdx.x;
    const int bh = blockIdx.y;
    const int b = bh >> 4, h = bh & 15;
    const int tid = threadIdx.x, lane = tid & 63, w = tid >> 6;
    const int l16 = lane & 15, lq = lane >> 4;

    __shared__ alignas(16) u16 sK[64 * 128];
    __shared__ alignas(16) u16 sVt[128 * 64];
    __shared__ alignas(16) u16 sP[4][16 * 64];

    const int rowbase = b * Ss;
    const int q0 = qt * 64;

    bf16x8 qf[4];
    {
        const u16* qp = qbuf + (size_t)(rowbase + q0 + w * 16 + l16) * 2048 + h * 128 + lq * 8;
#pragma unroll
        for (int c = 0; c < 4; c++) qf[c] = *(const bf16x8*)(qp + c * 32);
    }
    float mi[4], li[4];
    f32x4 o[8];
#pragma unroll
    for (int r = 0; r < 4; r++) { mi[r] = -1e30f; li[r] = 0.f; }
#pragma unroll
    for (int d = 0; d < 8; d++)
#pragma unroll
        for (int r = 0; r < 4; r++) o[d][r] = 0.f;

    const int sr = tid >> 2;          // key row 0..63
    const int sc = (tid & 3) * 32;    // K col segment
    const int vd = tid >> 1;          // V d-row 0..127
    const int vh = (tid & 1) * 32;    // key half

    for (int kt = 0; kt <= qt; ++kt) {
        __syncthreads();
        {
            const int krow = rowbase + kt * 64 + sr;
            const u16* src = (sc < 64)
                ? kvbuf + (size_t)krow * 3072 + h * 192 + sc
                : krbuf + (size_t)krow * 1024 + h * 64 + (sc - 64);
#pragma unroll
            for (int j = 0; j < 4; j++) {
                int byteoff = sr * 256 + (sc + j * 8) * 2;
                *(bf16x8*)((char*)sK + (byteoff ^ ((sr & 7) << 4))) = *(const bf16x8*)(src + j * 8);
            }
            const u16* vsrc = vT + (size_t)(h * 128 + vd) * MROWS + rowbase + kt * 64 + vh;
#pragma unroll
            for (int j = 0; j < 4; j++) {
                int byteoff = vd * 128 + (vh + j * 8) * 2;
                *(bf16x8*)((char*)sVt + (byteoff ^ ((vd & 7) << 4))) = *(const bf16x8*)(vsrc + j * 8);
            }
        }
        __syncthreads();

        // QK^T: 16 q-rows x 64 keys per wave
        f32x4 scf[4];
#pragma unroll
        for (int n = 0; n < 4; n++) {
#pragma unroll
            for (int r = 0; r < 4; r++) scf[n][r] = 0.f;
        }
        __builtin_amdgcn_s_setprio(1);
#pragma unroll
        for (int n = 0; n < 4; n++) {
#pragma unroll
            for (int c = 0; c < 4; c++) {
                int row = n * 16 + l16;
                int byteoff = row * 256 + (c * 32 + lq * 8) * 2;
                bf16x8 kf = *(const bf16x8*)((char*)sK + (byteoff ^ ((row & 7) << 4)));
                scf[n] = __builtin_amdgcn_mfma_f32_16x16x32_bf16(qf[c], kf, scf[n], 0, 0, 0);
            }
        }
        __builtin_amdgcn_s_setprio(0);
        const float scale = 0.08838834764831845f;
        float mnew[4];
#pragma unroll
        for (int r = 0; r < 4; r++) mnew[r] = mi[r];
        const int qg_base = q0 + w * 16 + lq * 4;
#pragma unroll
        for (int n = 0; n < 4; n++) {
            int kg = kt * 64 + n * 16 + l16;
#pragma unroll
            for (int r = 0; r < 4; r++) {
                float s = scf[n][r] * scale;
                s = (kg <= qg_base + r) ? s : -1e30f;
                scf[n][r] = s;
                mnew[r] = fmaxf(mnew[r], s);
            }
        }
#pragma unroll
        for (int off = 8; off; off >>= 1)
#pragma unroll
            for (int r = 0; r < 4; r++) mnew[r] = fmaxf(mnew[r], __shfl_xor(mnew[r], off, 64));
        float rs[4] = {0.f, 0.f, 0.f, 0.f};
#pragma unroll
        for (int n = 0; n < 4; n++)
#pragma unroll
            for (int r = 0; r < 4; r++) {
                float p = __expf(scf[n][r] - mnew[r]);
                scf[n][r] = p;
                rs[r] += p;
            }
#pragma unroll
        for (int off = 8; off; off >>= 1)
#pragma unroll
            for (int r = 0; r < 4; r++) rs[r] += __shfl_xor(rs[r], off, 64);
#pragma unroll
        for (int r = 0; r < 4; r++) {
            float f = __expf(mi[r] - mnew[r]);
            li[r] = li[r] * f + rs[r];
            mi[r] = mnew[r];
#pragma unroll
            for (int d = 0; d < 8; d++) o[d][r] *= f;
        }
        // P -> LDS (D-layout -> A-layout bounce)
#pragma unroll
        for (int n = 0; n < 4; n++)
#pragma unroll
            for (int r = 0; r < 4; r++) {
                int row = lq * 4 + r;
                int byteoff = row * 128 + (n * 16 + l16) * 2;
                *(u16*)((char*)sP[w] + (byteoff ^ ((row & 7) << 4))) = f2bf(scf[n][r]);
            }
        __syncthreads();
        // PV
        __builtin_amdgcn_s_setprio(1);
#pragma unroll
        for (int c = 0; c < 2; c++) {
            int pbyte = l16 * 128 + (c * 32 + lq * 8) * 2;
            bf16x8 pf = *(const bf16x8*)((char*)sP[w] + (pbyte ^ ((l16 & 7) << 4)));
#pragma unroll
            for (int d = 0; d < 8; d++) {
                int vrow = d * 16 + l16;
                int vbyte = vrow * 128 + (c * 32 + lq * 8) * 2;
                bf16x8 vf = *(const bf16x8*)((char*)sVt + (vbyte ^ ((vrow & 7) << 4)));
                o[d] = __builtin_amdgcn_mfma_f32_16x16x32_bf16(pf, vf, o[d], 0, 0, 0);
            }
        }
        __builtin_amdgcn_s_setprio(0);
    }
    // epilogue
    u16* op = obuf + (size_t)(rowbase + q0 + w * 16) * 2048 + h * 128;
#pragma unroll
    for (int r = 0; r < 4; r++) {
        float invl = 1.f / li[r];
        int row = lq * 4 + r;
#pragma unroll
        for (int d = 0; d < 8; d++)
            op[(size_t)row * 2048 + d * 16 + l16] = f2bf(o[d][r] * invl);
    }
}

// ---------------- launch ----------------
extern "C" void kernel_launch(void* const* d_in, const int* in_sizes, int n_in,
                              void* d_out, int out_size, void* d_ws, size_t ws_size,
                              hipStream_t stream) {
    const float* x        = (const float*)d_in[0];
    const float* q_down_w = (const float*)d_in[1];
    const float* q_down_b = (const float*)d_in[2];
    const float* q_norm_w = (const float*)d_in[3];
    const float* q_up_w   = (const float*)d_in[4];
    const float* q_up_b   = (const float*)d_in[5];
    const float* kv_down_w= (const float*)d_in[6];
    const float* kv_down_b= (const float*)d_in[7];
    const float* kv_norm_w= (const float*)d_in[8];
    const float* kv_up_w  = (const float*)d_in[9];
    const float* kv_up_b  = (const float*)d_in[10];
    const float* k_rope_w = (const float*)d_in[11];
    const float* k_rope_b = (const float*)d_in[12];
    const float* out_w    = (const float*)d_in[13];
    const float* out_b    = (const float*)d_in[14];

    char* ws = (char*)d_ws;
    u16* xbf    = (u16*)(ws + 0);          // 16.78 MB ; later reused as vT
    u16* wcat   = (u16*)(ws + 16777216);   // 10.49 MB (2560x2048 bf16)
    u16* quw    = (u16*)(ws + 27262976);   // 4.19 MB
    u16* kvuw   = (u16*)(ws + 31457280);   // 3.15 MB
    u16* outw   = (u16*)(ws + 34603008);   // 8.39 MB
    float* bcat = (float*)(ws + 42991616); // 10 KB (pad to 16 KB)
    float* dcat = (float*)(ws + 43008000); // 25.17 MB (4096x1536 f32); reused as attnbuf
    u16* cq     = (u16*)(ws + 68173824);   // 8.39 MB
    u16* ckv    = (u16*)(ws + 76562432);   // 4.19 MB
    u16* qbuf   = (u16*)(ws + 80756736);   // 16.78 MB
    u16* kvbuf  = (u16*)(ws + 97533952);   // 25.17 MB
    u16* krbuf  = (u16*)(ws + 122699776);  // 8.39 MB  (end 131,088,384)
    u16* vT     = (u16*)(ws + 0);          // alias xbf (dead after gemm_down)
    u16* attnbuf= (u16*)(ws + 43008000);   // alias dcat (dead after rmsnorms)

    auto cvt = [&](const float* src, u16* dst, int n) {
        int n4 = n / 4;
        cvt_f32_bf16<<<(n4 + 255) / 256, 256, 0, stream>>>(src, dst, n4);
    };
    cvt(x,         xbf,  MROWS * DM);
    cvt(q_down_w,  wcat,                1024 * 2048);
    cvt(kv_down_w, wcat + 1024 * 2048,  512 * 2048);
    cvt(k_rope_w,  wcat + 1536 * 2048,  1024 * 2048);
    cvt(q_up_w,    quw,  2048 * 1024);
    cvt(kv_up_w,   kvuw, 3072 * 512);
    cvt(out_w,     outw, 2048 * 2048);
    build_bcat<<<10, 256, 0, stream>>>(q_down_b, kv_down_b, k_rope_b, bcat);

    // fused down projections: x @ [q_down|kv_down|k_rope]^T
    gemm_down<<<dim3(20, 32), 256, 0, stream>>>(xbf, wcat, bcat, dcat, krbuf);
    rmsnorm_bf16<1024><<<MROWS, 256, 0, stream>>>(dcat, 1536, q_norm_w, cq);
    rmsnorm_bf16<512><<<MROWS, 256, 0, stream>>>(dcat + 1024, 1536, kv_norm_w, ckv);
    // up projections
    gemm_bt<u16><<<dim3(16, 32), 256, 0, stream>>>(cq, quw, q_up_b, qbuf, MROWS, 2048, 1024);
    gemm_bt<u16><<<dim3(24, 32), 256, 0, stream>>>(ckv, kvuw, kv_up_b, kvbuf, MROWS, 3072, 512);
    // V transpose (vT aliases xbf; xbf dead after gemm_down)
    transpose_v<<<dim3(64, 32), 256, 0, stream>>>(kvbuf, vT);
    // attention
    mla_attn<<<dim3(Ss / 64, Bb * NH), 256, 0, stream>>>(qbuf, kvbuf, krbuf, vT, attnbuf);
    // output projection
    gemm_bt<float><<<dim3(16, 32), 256, 0, stream>>>(attnbuf, outw, out_b, (float*)d_out, MROWS, 2048, 2048);
}

// Round 3
// 298.725 us; speedup vs baseline: 1.6974x; 1.3227x over previous
//
#include <hip/hip_runtime.h>
#include <hip/hip_bf16.h>

typedef __attribute__((ext_vector_type(8))) short bf16x8;
typedef __attribute__((ext_vector_type(4))) float f32x4;
typedef unsigned short u16;

#define RMS_EPS 1.1920929e-07f

constexpr int Bb = 2, Ss = 2048, DM = 2048, NH = 16;
constexpr int MROWS = Bb * Ss; // 4096

__device__ __forceinline__ u16 f2bf(float f) {
    __hip_bfloat16 h = __float2bfloat16(f);
    return *reinterpret_cast<u16*>(&h);
}

__device__ __forceinline__ void gload16(const void* g, void* l) {
    __builtin_amdgcn_global_load_lds(
        (const __attribute__((address_space(1))) unsigned int*)g,
        (__attribute__((address_space(3))) unsigned int*)l, 16, 0, 0);
}

// ---------------- fp32 -> bf16 convert ----------------
__global__ void cvt_f32_bf16(const float* __restrict__ in, u16* __restrict__ out, int n4) {
    int i = blockIdx.x * 256 + threadIdx.x;
    if (i >= n4) return;
    float4 v = reinterpret_cast<const float4*>(in)[i];
    ushort4 o;
    o.x = f2bf(v.x); o.y = f2bf(v.y); o.z = f2bf(v.z); o.w = f2bf(v.w);
    reinterpret_cast<ushort4*>(out)[i] = o;
}

__global__ void build_bcat(const float* __restrict__ qb, const float* __restrict__ kvb,
                           const float* __restrict__ krb, float* __restrict__ bcat) {
    int i = blockIdx.x * 256 + threadIdx.x;
    if (i < 1024) bcat[i] = qb[i];
    else if (i < 1536) bcat[i] = kvb[i - 1024];
    else if (i < 2560) bcat[i] = krb[i - 1536];
}

// ---------------- GEMM: C(M,N) = A(M,K) * Bt(N,K)^T + bias ----------------
template <typename OutT>
__global__ __launch_bounds__(256) void gemm_bt(
    const u16* __restrict__ A, const u16* __restrict__ Bt,
    const float* __restrict__ bias, OutT* __restrict__ C,
    int M, int N, int K)
{
    __shared__ alignas(16) u16 sA[128 * 32];
    __shared__ alignas(16) u16 sB[128 * 32];
    const int tid = threadIdx.x;
    const int lane = tid & 63;
    const int w = tid >> 6;
    const int wr = w >> 1, wc = w & 1;
    const int l16 = lane & 15, lq = lane >> 4;
    const int tileM = blockIdx.y * 128;
    const int tileN = blockIdx.x * 128;

    f32x4 acc[4][4];
#pragma unroll
    for (int m = 0; m < 4; m++)
#pragma unroll
        for (int n = 0; n < 4; n++)
#pragma unroll
            for (int r = 0; r < 4; r++) acc[m][n][r] = 0.f;

    const int srow = w * 16 + (lane >> 2);
    const int scol = (lane & 3) * 8;
    const u16* gA0 = A + (size_t)(tileM + srow) * K + scol;
    const u16* gA1 = A + (size_t)(tileM + srow + 64) * K + scol;
    const u16* gB0 = Bt + (size_t)(tileN + srow) * K + scol;
    const u16* gB1 = Bt + (size_t)(tileN + srow + 64) * K + scol;
    u16* lA0 = sA + w * 512;
    u16* lA1 = sA + 2048 + w * 512;
    u16* lB0 = sB + w * 512;
    u16* lB1 = sB + 2048 + w * 512;

    int aoff[4], boff[4];
#pragma unroll
    for (int m = 0; m < 4; m++) aoff[m] = (wr * 64 + m * 16 + l16) * 32 + lq * 8;
#pragma unroll
    for (int n = 0; n < 4; n++) boff[n] = (wc * 64 + n * 16 + l16) * 32 + lq * 8;

    const int nk = K >> 5;
    for (int kk = 0; kk < nk; ++kk) {
        __syncthreads();
        gload16(gA0, lA0);
        gload16(gA1, lA1);
        gload16(gB0, lB0);
        gload16(gB1, lB1);
        gA0 += 32; gA1 += 32; gB0 += 32; gB1 += 32;
        __syncthreads();
        bf16x8 af[4], bfr[4];
#pragma unroll
        for (int m = 0; m < 4; m++) af[m] = *(const bf16x8*)&sA[aoff[m]];
#pragma unroll
        for (int n = 0; n < 4; n++) bfr[n] = *(const bf16x8*)&sB[boff[n]];
        __builtin_amdgcn_s_setprio(1);
#pragma unroll
        for (int m = 0; m < 4; m++)
#pragma unroll
            for (int n = 0; n < 4; n++)
                acc[m][n] = __builtin_amdgcn_mfma_f32_16x16x32_bf16(af[m], bfr[n], acc[m][n], 0, 0, 0);
        __builtin_amdgcn_s_setprio(0);
    }

#pragma unroll
    for (int n = 0; n < 4; n++) {
        int col = tileN + wc * 64 + n * 16 + l16;
        float bv = bias ? bias[col] : 0.f;
#pragma unroll
        for (int m = 0; m < 4; m++) {
            int rowb = tileM + wr * 64 + m * 16 + (lq << 2);
#pragma unroll
            for (int r = 0; r < 4; r++) {
                float v = acc[m][n][r] + bv;
                if constexpr (sizeof(OutT) == 2)
                    C[(size_t)(rowb + r) * N + col] = (OutT)f2bf(v);
                else
                    C[(size_t)(rowb + r) * N + col] = (OutT)v;
            }
        }
    }
}

// ---------------- fused down-proj GEMM: N=2560 (1024 q | 512 kv | 1024 rope) ----
__global__ __launch_bounds__(256) void gemm_down(
    const u16* __restrict__ A, const u16* __restrict__ Bt,
    const float* __restrict__ bcat, float* __restrict__ dcat,
    u16* __restrict__ krbuf)
{
    constexpr int K = 2048;
    __shared__ alignas(16) u16 sA[128 * 32];
    __shared__ alignas(16) u16 sB[128 * 32];
    const int tid = threadIdx.x;
    const int lane = tid & 63;
    const int w = tid >> 6;
    const int wr = w >> 1, wc = w & 1;
    const int l16 = lane & 15, lq = lane >> 4;
    const int tileM = blockIdx.y * 128;
    const int tileN = blockIdx.x * 128;

    f32x4 acc[4][4];
#pragma unroll
    for (int m = 0; m < 4; m++)
#pragma unroll
        for (int n = 0; n < 4; n++)
#pragma unroll
            for (int r = 0; r < 4; r++) acc[m][n][r] = 0.f;

    const int srow = w * 16 + (lane >> 2);
    const int scol = (lane & 3) * 8;
    const u16* gA0 = A + (size_t)(tileM + srow) * K + scol;
    const u16* gA1 = A + (size_t)(tileM + srow + 64) * K + scol;
    const u16* gB0 = Bt + (size_t)(tileN + srow) * K + scol;
    const u16* gB1 = Bt + (size_t)(tileN + srow + 64) * K + scol;
    u16* lA0 = sA + w * 512;
    u16* lA1 = sA + 2048 + w * 512;
    u16* lB0 = sB + w * 512;
    u16* lB1 = sB + 2048 + w * 512;

    int aoff[4], boff[4];
#pragma unroll
    for (int m = 0; m < 4; m++) aoff[m] = (wr * 64 + m * 16 + l16) * 32 + lq * 8;
#pragma unroll
    for (int n = 0; n < 4; n++) boff[n] = (wc * 64 + n * 16 + l16) * 32 + lq * 8;

    const int nk = K >> 5;
    for (int kk = 0; kk < nk; ++kk) {
        __syncthreads();
        gload16(gA0, lA0);
        gload16(gA1, lA1);
        gload16(gB0, lB0);
        gload16(gB1, lB1);
        gA0 += 32; gA1 += 32; gB0 += 32; gB1 += 32;
        __syncthreads();
        bf16x8 af[4], bfr[4];
#pragma unroll
        for (int m = 0; m < 4; m++) af[m] = *(const bf16x8*)&sA[aoff[m]];
#pragma unroll
        for (int n = 0; n < 4; n++) bfr[n] = *(const bf16x8*)&sB[boff[n]];
        __builtin_amdgcn_s_setprio(1);
#pragma unroll
        for (int m = 0; m < 4; m++)
#pragma unroll
            for (int n = 0; n < 4; n++)
                acc[m][n] = __builtin_amdgcn_mfma_f32_16x16x32_bf16(af[m], bfr[n], acc[m][n], 0, 0, 0);
        __builtin_amdgcn_s_setprio(0);
    }

    const bool isrope = (tileN >= 1536);
#pragma unroll
    for (int n = 0; n < 4; n++) {
        int col = tileN + wc * 64 + n * 16 + l16;
        float bv = bcat[col];
#pragma unroll
        for (int m = 0; m < 4; m++) {
            int rowb = tileM + wr * 64 + m * 16 + (lq << 2);
#pragma unroll
            for (int r = 0; r < 4; r++) {
                float v = acc[m][n][r] + bv;
                if (!isrope) dcat[(size_t)(rowb + r) * 1536 + col] = v;
                else         krbuf[(size_t)(rowb + r) * 1024 + (col - 1536)] = f2bf(v);
            }
        }
    }
}

// ---------------- RMS norm (row-wise, strided in), fp32 in -> bf16 out --------
template <int C>
__global__ __launch_bounds__(256) void rmsnorm_bf16(
    const float* __restrict__ in, int istride, const float* __restrict__ wgt, u16* __restrict__ out)
{
    const int row = blockIdx.x;
    const int tid = threadIdx.x;
    constexpr int PER = C / 256;
    const float* p = in + (size_t)row * istride;
    float v[PER];
    float ss = 0.f;
#pragma unroll
    for (int i = 0; i < PER; i++) { v[i] = p[tid + i * 256]; ss += v[i] * v[i]; }
#pragma unroll
    for (int o = 32; o; o >>= 1) ss += __shfl_xor(ss, o, 64);
    __shared__ float red[4];
    if ((tid & 63) == 0) red[tid >> 6] = ss;
    __syncthreads();
    float tot = red[0] + red[1] + red[2] + red[3];
    float inv = rsqrtf(tot / (float)C + RMS_EPS);
    u16* q = out + (size_t)row * C;
#pragma unroll
    for (int i = 0; i < PER; i++) {
        int c = tid + i * 256;
        q[c] = f2bf(v[i] * inv * wgt[c]);
    }
}

// ---------------- V transpose: kvbuf[token][h*192+64+d] -> vT[(h*128+d)*4096+token]
__global__ __launch_bounds__(256) void transpose_v(
    const u16* __restrict__ kvbuf, u16* __restrict__ vT)
{
    __shared__ alignas(16) u16 tile[64][72];
    const int tid = threadIdx.x;
    const int t0 = blockIdx.x * 64;
    const int h = blockIdx.y >> 1, dh = blockIdx.y & 1;
    const int trow = tid >> 2, c8 = (tid & 3) * 8;
    const u16* src = kvbuf + (size_t)(t0 + trow) * 3072 + h * 192 + 64 + dh * 64 + c8;
    *(bf16x8*)&tile[trow][c8]      = *(const bf16x8*)src;
    *(bf16x8*)&tile[trow][c8 + 32] = *(const bf16x8*)(src + 32);
    __syncthreads();
    const int drow = tid >> 2, tc8 = (tid & 3) * 8;
    bf16x8 a, b2;
#pragma unroll
    for (int j = 0; j < 8; j++) {
        a[j]  = (short)tile[tc8 + j][drow];
        b2[j] = (short)tile[tc8 + 32 + j][drow];
    }
    u16* dst = vT + (size_t)(h * 128 + dh * 64 + drow) * MROWS + t0 + tc8;
    *(bf16x8*)dst = a;
    *(bf16x8*)(dst + 32) = b2;
}

// ---------------- causal flash attention (swapped-operand, paired q-tiles) ----
// grid: (16 pairs, 32 bh); block 256 (4 waves x 16 q-rows). D=128, KT=64.
// Pair p handles q-tiles p and 31-p -> every block does exactly 33 k-tile iters.
__global__ __launch_bounds__(256) void mla_attn(
    const u16* __restrict__ qbuf,   // (4096, 2048) head-major h*128
    const u16* __restrict__ kvbuf,  // (4096, 3072) per head 192: knope(64) v(128)
    const u16* __restrict__ krbuf,  // (4096, 1024) per head 64
    const u16* __restrict__ vT,     // (h*128+d, 4096 tokens)
    u16* __restrict__ obuf)         // (4096, 2048)
{
    const int p = blockIdx.x;
    const int bh = blockIdx.y;
    const int b = bh >> 4, h = bh & 15;
    const int tid = threadIdx.x, lane = tid & 63, w = tid >> 6;
    const int l16 = lane & 15, lq = lane >> 4;

    __shared__ alignas(16) u16 sK[64 * 128];
    __shared__ alignas(16) u16 sVt[128 * 64];
    __shared__ alignas(16) u16 sPT[4][16 * 64];

    const int rowbase = b * Ss;
    char* pbase = (char*)sPT[w];

    // staging thread mapping
    const int sr = tid >> 2;          // key row 0..63
    const int sc = (tid & 3) * 32;    // K col segment
    const int vd = tid >> 1;          // V d-row 0..127
    const int vh = (tid & 1) * 32;    // key half
    const float scale = 0.08838834764831845f;

#pragma unroll
    for (int half = 0; half < 2; ++half) {
        const int qt = half ? (31 - p) : p;
        const int q0 = qt * 64;

        bf16x8 qf[4];
        {
            const u16* qp = qbuf + (size_t)(rowbase + q0 + w * 16 + l16) * 2048 + h * 128 + lq * 8;
#pragma unroll
            for (int c = 0; c < 4; c++) qf[c] = *(const bf16x8*)(qp + c * 32);
        }
        float mi = -1e30f, li = 0.f;
        f32x4 o[8];
#pragma unroll
        for (int d = 0; d < 8; d++)
#pragma unroll
            for (int r = 0; r < 4; r++) o[d][r] = 0.f;

        bf16x8 kr[4], vr[4];
        // prologue: load tile kt=0 into regs
        {
            const int krow = rowbase + sr;
            const u16* src = (sc < 64)
                ? kvbuf + (size_t)krow * 3072 + h * 192 + sc
                : krbuf + (size_t)krow * 1024 + h * 64 + (sc - 64);
#pragma unroll
            for (int j = 0; j < 4; j++) kr[j] = *(const bf16x8*)(src + j * 8);
            const u16* vsrc = vT + (size_t)(h * 128 + vd) * MROWS + rowbase + vh;
#pragma unroll
            for (int j = 0; j < 4; j++) vr[j] = *(const bf16x8*)(vsrc + j * 8);
        }

        for (int kt = 0; kt <= qt; ++kt) {
            __syncthreads();
#pragma unroll
            for (int j = 0; j < 4; j++) {
                int byteoff = sr * 256 + (sc + j * 8) * 2;
                *(bf16x8*)((char*)sK + (byteoff ^ ((sr & 7) << 4))) = kr[j];
            }
#pragma unroll
            for (int j = 0; j < 4; j++) {
                int byteoff = vd * 128 + (vh + j * 8) * 2;
                *(bf16x8*)((char*)sVt + (byteoff ^ ((vd & 7) << 4))) = vr[j];
            }
            __syncthreads();
            // async-prefetch next tile into regs (hides under compute)
            if (kt < qt) {
                const int krow = rowbase + (kt + 1) * 64 + sr;
                const u16* src = (sc < 64)
                    ? kvbuf + (size_t)krow * 3072 + h * 192 + sc
                    : krbuf + (size_t)krow * 1024 + h * 64 + (sc - 64);
#pragma unroll
                for (int j = 0; j < 4; j++) kr[j] = *(const bf16x8*)(src + j * 8);
                const u16* vsrc = vT + (size_t)(h * 128 + vd) * MROWS + rowbase + (kt + 1) * 64 + vh;
#pragma unroll
                for (int j = 0; j < 4; j++) vr[j] = *(const bf16x8*)(vsrc + j * 8);
            }

            // QK^T swapped: A=K, B=Q -> D[k][q]; lane: q=l16, k=n*16+lq*4+r
            f32x4 scf[4];
#pragma unroll
            for (int n = 0; n < 4; n++)
#pragma unroll
                for (int r = 0; r < 4; r++) scf[n][r] = 0.f;
            __builtin_amdgcn_s_setprio(1);
#pragma unroll
            for (int n = 0; n < 4; n++) {
#pragma unroll
                for (int c = 0; c < 4; c++) {
                    int row = n * 16 + l16;
                    int byteoff = row * 256 + (c * 32 + lq * 8) * 2;
                    bf16x8 kf = *(const bf16x8*)((char*)sK + (byteoff ^ ((row & 7) << 4)));
                    scf[n] = __builtin_amdgcn_mfma_f32_16x16x32_bf16(kf, qf[c], scf[n], 0, 0, 0);
                }
            }
            __builtin_amdgcn_s_setprio(0);

            // mask + online softmax, per-lane row q = l16
            const int qg = q0 + w * 16 + l16;
            float mnew = mi;
#pragma unroll
            for (int n = 0; n < 4; n++)
#pragma unroll
                for (int r = 0; r < 4; r++) {
                    int kg = kt * 64 + n * 16 + lq * 4 + r;
                    float s = scf[n][r] * scale;
                    s = (kg <= qg) ? s : -1e30f;
                    scf[n][r] = s;
                    mnew = fmaxf(mnew, s);
                }
            mnew = fmaxf(mnew, __shfl_xor(mnew, 16, 64));
            mnew = fmaxf(mnew, __shfl_xor(mnew, 32, 64));
            float rs = 0.f;
#pragma unroll
            for (int n = 0; n < 4; n++)
#pragma unroll
                for (int r = 0; r < 4; r++) {
                    float pv = __expf(scf[n][r] - mnew);
                    scf[n][r] = pv;
                    rs += pv;
                }
            rs += __shfl_xor(rs, 16, 64);
            rs += __shfl_xor(rs, 32, 64);
            float f = __expf(mi - mnew);
            li = li * f + rs;
            mi = mnew;
#pragma unroll
            for (int d = 0; d < 8; d++)
#pragma unroll
                for (int r = 0; r < 4; r++) o[d][r] *= f;

            // P^T -> wave-private LDS (vectorized 8B writes), no barrier needed
#pragma unroll
            for (int n = 0; n < 4; n++) {
                ushort4 pk;
                pk.x = f2bf(scf[n][0]); pk.y = f2bf(scf[n][1]);
                pk.z = f2bf(scf[n][2]); pk.w = f2bf(scf[n][3]);
                int byteoff = l16 * 128 + n * 32 + lq * 8;
                *(ushort4*)(pbase + (byteoff ^ ((l16 & 7) << 4))) = pk;
            }
            // PV swapped: A=V^T, B=P^T -> D[d][q]
            __builtin_amdgcn_s_setprio(1);
#pragma unroll
            for (int c = 0; c < 2; c++) {
                int pbyte = l16 * 128 + (c * 32 + lq * 8) * 2;
                bf16x8 pf = *(const bf16x8*)(pbase + (pbyte ^ ((l16 & 7) << 4)));
#pragma unroll
                for (int d = 0; d < 8; d++) {
                    int vrow = d * 16 + l16;
                    int vbyte = vrow * 128 + (c * 32 + lq * 8) * 2;
                    bf16x8 vf = *(const bf16x8*)((char*)sVt + (vbyte ^ ((vrow & 7) << 4)));
                    o[d] = __builtin_amdgcn_mfma_f32_16x16x32_bf16(vf, pf, o[d], 0, 0, 0);
                }
            }
            __builtin_amdgcn_s_setprio(0);
        }
        // epilogue: lane holds O^T[d][q=l16]; d = db*16 + lq*4 + r
        float invl = 1.f / li;
        u16* op = obuf + (size_t)(rowbase + q0 + w * 16 + l16) * 2048 + h * 128;
#pragma unroll
        for (int d = 0; d < 8; d++) {
            ushort4 ok;
            ok.x = f2bf(o[d][0] * invl); ok.y = f2bf(o[d][1] * invl);
            ok.z = f2bf(o[d][2] * invl); ok.w = f2bf(o[d][3] * invl);
            *(ushort4*)(op + d * 16 + lq * 4) = ok;
        }
    }
}

// ---------------- launch ----------------
extern "C" void kernel_launch(void* const* d_in, const int* in_sizes, int n_in,
                              void* d_out, int out_size, void* d_ws, size_t ws_size,
                              hipStream_t stream) {
    const float* x        = (const float*)d_in[0];
    const float* q_down_w = (const float*)d_in[1];
    const float* q_down_b = (const float*)d_in[2];
    const float* q_norm_w = (const float*)d_in[3];
    const float* q_up_w   = (const float*)d_in[4];
    const float* q_up_b   = (const float*)d_in[5];
    const float* kv_down_w= (const float*)d_in[6];
    const float* kv_down_b= (const float*)d_in[7];
    const float* kv_norm_w= (const float*)d_in[8];
    const float* kv_up_w  = (const float*)d_in[9];
    const float* kv_up_b  = (const float*)d_in[10];
    const float* k_rope_w = (const float*)d_in[11];
    const float* k_rope_b = (const float*)d_in[12];
    const float* out_w    = (const float*)d_in[13];
    const float* out_b    = (const float*)d_in[14];

    char* ws = (char*)d_ws;
    u16* xbf    = (u16*)(ws + 0);          // 16.78 MB ; later reused as vT
    u16* wcat   = (u16*)(ws + 16777216);   // 10.49 MB (2560x2048 bf16)
    u16* quw    = (u16*)(ws + 27262976);   // 4.19 MB
    u16* kvuw   = (u16*)(ws + 31457280);   // 3.15 MB
    u16* outw   = (u16*)(ws + 34603008);   // 8.39 MB
    float* bcat = (float*)(ws + 42991616); // 10 KB (pad to 16 KB)
    float* dcat = (float*)(ws + 43008000); // 25.17 MB (4096x1536 f32); reused as attnbuf
    u16* cq     = (u16*)(ws + 68173824);   // 8.39 MB
    u16* ckv    = (u16*)(ws + 76562432);   // 4.19 MB
    u16* qbuf   = (u16*)(ws + 80756736);   // 16.78 MB
    u16* kvbuf  = (u16*)(ws + 97533952);   // 25.17 MB
    u16* krbuf  = (u16*)(ws + 122699776);  // 8.39 MB  (end 131,088,384)
    u16* vT     = (u16*)(ws + 0);          // alias xbf (dead after gemm_down)
    u16* attnbuf= (u16*)(ws + 43008000);   // alias dcat (dead after rmsnorms)

    auto cvt = [&](const float* src, u16* dst, int n) {
        int n4 = n / 4;
        cvt_f32_bf16<<<(n4 + 255) / 256, 256, 0, stream>>>(src, dst, n4);
    };
    cvt(x,         xbf,  MROWS * DM);
    cvt(q_down_w,  wcat,                1024 * 2048);
    cvt(kv_down_w, wcat + 1024 * 2048,  512 * 2048);
    cvt(k_rope_w,  wcat + 1536 * 2048,  1024 * 2048);
    cvt(q_up_w,    quw,  2048 * 1024);
    cvt(kv_up_w,   kvuw, 3072 * 512);
    cvt(out_w,     outw, 2048 * 2048);
    build_bcat<<<10, 256, 0, stream>>>(q_down_b, kv_down_b, k_rope_b, bcat);

    // fused down projections: x @ [q_down|kv_down|k_rope]^T
    gemm_down<<<dim3(20, 32), 256, 0, stream>>>(xbf, wcat, bcat, dcat, krbuf);
    rmsnorm_bf16<1024><<<MROWS, 256, 0, stream>>>(dcat, 1536, q_norm_w, cq);
    rmsnorm_bf16<512><<<MROWS, 256, 0, stream>>>(dcat + 1024, 1536, kv_norm_w, ckv);
    // up projections
    gemm_bt<u16><<<dim3(16, 32), 256, 0, stream>>>(cq, quw, q_up_b, qbuf, MROWS, 2048, 1024);
    gemm_bt<u16><<<dim3(24, 32), 256, 0, stream>>>(ckv, kvuw, kv_up_b, kvbuf, MROWS, 3072, 512);
    // V transpose (vT aliases xbf; xbf dead after gemm_down)
    transpose_v<<<dim3(64, 32), 256, 0, stream>>>(kvbuf, vT);
    // attention (paired q-tiles for perfect balance: 33 k-tiles per block)
    mla_attn<<<dim3(16, Bb * NH), 256, 0, stream>>>(qbuf, kvbuf, krbuf, vT, attnbuf);
    // output projection
    gemm_bt<float><<<dim3(16, 32), 256, 0, stream>>>(attnbuf, outw, out_b, (float*)d_out, MROWS, 2048, 2048);
}

// Round 4
// 285.405 us; speedup vs baseline: 1.7766x; 1.0467x over previous
//
#include <hip/hip_runtime.h>
#include <hip/hip_bf16.h>

typedef __attribute__((ext_vector_type(8))) short bf16x8;
typedef __attribute__((ext_vector_type(4))) float f32x4;
typedef unsigned short u16;

#define RMS_EPS 1.1920929e-07f

constexpr int Bb = 2, Ss = 2048, DM = 2048, NH = 16;
constexpr int MROWS = Bb * Ss; // 4096

__device__ __forceinline__ u16 f2bf(float f) {
    __hip_bfloat16 h = __float2bfloat16(f);
    return *reinterpret_cast<u16*>(&h);
}

__device__ __forceinline__ float exp2_fast(float x) {
    float r; asm("v_exp_f32 %0, %1" : "=v"(r) : "v"(x)); return r;
}

__device__ __forceinline__ void gload16(const void* g, void* l) {
    __builtin_amdgcn_global_load_lds(
        (const __attribute__((address_space(1))) unsigned int*)g,
        (__attribute__((address_space(3))) unsigned int*)l, 16, 0, 0);
}

// ---------------- merged fp32 -> bf16 convert (7 segments, sizes fixed) -------
__global__ __launch_bounds__(256) void cvt_all(
    const float* __restrict__ s0, u16* __restrict__ d0,
    const float* __restrict__ s1, u16* __restrict__ d1,
    const float* __restrict__ s2, u16* __restrict__ d2,
    const float* __restrict__ s3, u16* __restrict__ d3,
    const float* __restrict__ s4, u16* __restrict__ d4,
    const float* __restrict__ s5, u16* __restrict__ d5,
    const float* __restrict__ s6, u16* __restrict__ d6)
{
    int i = blockIdx.x * 256 + threadIdx.x;   // float4 index; grid covers exactly 5373952
    const float* s; u16* d; int off;
    if (i < 2097152)      { s = s0; d = d0; off = 0; }
    else if (i < 2621440) { s = s1; d = d1; off = 2097152; }
    else if (i < 2883584) { s = s2; d = d2; off = 2621440; }
    else if (i < 3407872) { s = s3; d = d3; off = 2883584; }
    else if (i < 3932160) { s = s4; d = d4; off = 3407872; }
    else if (i < 4325376) { s = s5; d = d5; off = 3932160; }
    else                  { s = s6; d = d6; off = 4325376; }
    int j = i - off;
    float4 v = reinterpret_cast<const float4*>(s)[j];
    ushort4 o;
    o.x = f2bf(v.x); o.y = f2bf(v.y); o.z = f2bf(v.z); o.w = f2bf(v.w);
    reinterpret_cast<ushort4*>(d)[j] = o;
}

__global__ void build_bcat(const float* __restrict__ qb, const float* __restrict__ kvb,
                           const float* __restrict__ krb, float* __restrict__ bcat) {
    int i = blockIdx.x * 256 + threadIdx.x;
    if (i < 1024) bcat[i] = qb[i];
    else if (i < 1536) bcat[i] = kvb[i - 1024];
    else if (i < 2560) bcat[i] = krb[i - 1536];
}

// ---------------- GEMM: C(M,N) = A(M,K) * Bt(N,K)^T + bias ----------------
template <typename OutT>
__global__ __launch_bounds__(256) void gemm_bt(
    const u16* __restrict__ A, const u16* __restrict__ Bt,
    const float* __restrict__ bias, OutT* __restrict__ C,
    int M, int N, int K)
{
    __shared__ alignas(16) u16 sA[128 * 32];
    __shared__ alignas(16) u16 sB[128 * 32];
    const int tid = threadIdx.x;
    const int lane = tid & 63;
    const int w = tid >> 6;
    const int wr = w >> 1, wc = w & 1;
    const int l16 = lane & 15, lq = lane >> 4;
    const int tileM = blockIdx.y * 128;
    const int tileN = blockIdx.x * 128;

    f32x4 acc[4][4];
#pragma unroll
    for (int m = 0; m < 4; m++)
#pragma unroll
        for (int n = 0; n < 4; n++)
#pragma unroll
            for (int r = 0; r < 4; r++) acc[m][n][r] = 0.f;

    const int srow = w * 16 + (lane >> 2);
    const int scol = (lane & 3) * 8;
    const u16* gA0 = A + (size_t)(tileM + srow) * K + scol;
    const u16* gA1 = A + (size_t)(tileM + srow + 64) * K + scol;
    const u16* gB0 = Bt + (size_t)(tileN + srow) * K + scol;
    const u16* gB1 = Bt + (size_t)(tileN + srow + 64) * K + scol;
    u16* lA0 = sA + w * 512;
    u16* lA1 = sA + 2048 + w * 512;
    u16* lB0 = sB + w * 512;
    u16* lB1 = sB + 2048 + w * 512;

    int aoff[4], boff[4];
#pragma unroll
    for (int m = 0; m < 4; m++) aoff[m] = (wr * 64 + m * 16 + l16) * 32 + lq * 8;
#pragma unroll
    for (int n = 0; n < 4; n++) boff[n] = (wc * 64 + n * 16 + l16) * 32 + lq * 8;

    const int nk = K >> 5;
    for (int kk = 0; kk < nk; ++kk) {
        __syncthreads();
        gload16(gA0, lA0);
        gload16(gA1, lA1);
        gload16(gB0, lB0);
        gload16(gB1, lB1);
        gA0 += 32; gA1 += 32; gB0 += 32; gB1 += 32;
        __syncthreads();
        bf16x8 af[4], bfr[4];
#pragma unroll
        for (int m = 0; m < 4; m++) af[m] = *(const bf16x8*)&sA[aoff[m]];
#pragma unroll
        for (int n = 0; n < 4; n++) bfr[n] = *(const bf16x8*)&sB[boff[n]];
        __builtin_amdgcn_s_setprio(1);
#pragma unroll
        for (int m = 0; m < 4; m++)
#pragma unroll
            for (int n = 0; n < 4; n++)
                acc[m][n] = __builtin_amdgcn_mfma_f32_16x16x32_bf16(af[m], bfr[n], acc[m][n], 0, 0, 0);
        __builtin_amdgcn_s_setprio(0);
    }

#pragma unroll
    for (int n = 0; n < 4; n++) {
        int col = tileN + wc * 64 + n * 16 + l16;
        float bv = bias ? bias[col] : 0.f;
#pragma unroll
        for (int m = 0; m < 4; m++) {
            int rowb = tileM + wr * 64 + m * 16 + (lq << 2);
#pragma unroll
            for (int r = 0; r < 4; r++) {
                float v = acc[m][n][r] + bv;
                if constexpr (sizeof(OutT) == 2)
                    C[(size_t)(rowb + r) * N + col] = (OutT)f2bf(v);
                else
                    C[(size_t)(rowb + r) * N + col] = (OutT)v;
            }
        }
    }
}

// ---------------- fused down-proj GEMM: N=2560 (1024 q | 512 kv | 1024 rope) ----
__global__ __launch_bounds__(256) void gemm_down(
    const u16* __restrict__ A, const u16* __restrict__ Bt,
    const float* __restrict__ bcat, float* __restrict__ dcat,
    u16* __restrict__ krbuf)
{
    constexpr int K = 2048;
    __shared__ alignas(16) u16 sA[128 * 32];
    __shared__ alignas(16) u16 sB[128 * 32];
    const int tid = threadIdx.x;
    const int lane = tid & 63;
    const int w = tid >> 6;
    const int wr = w >> 1, wc = w & 1;
    const int l16 = lane & 15, lq = lane >> 4;
    const int tileM = blockIdx.y * 128;
    const int tileN = blockIdx.x * 128;

    f32x4 acc[4][4];
#pragma unroll
    for (int m = 0; m < 4; m++)
#pragma unroll
        for (int n = 0; n < 4; n++)
#pragma unroll
            for (int r = 0; r < 4; r++) acc[m][n][r] = 0.f;

    const int srow = w * 16 + (lane >> 2);
    const int scol = (lane & 3) * 8;
    const u16* gA0 = A + (size_t)(tileM + srow) * K + scol;
    const u16* gA1 = A + (size_t)(tileM + srow + 64) * K + scol;
    const u16* gB0 = Bt + (size_t)(tileN + srow) * K + scol;
    const u16* gB1 = Bt + (size_t)(tileN + srow + 64) * K + scol;
    u16* lA0 = sA + w * 512;
    u16* lA1 = sA + 2048 + w * 512;
    u16* lB0 = sB + w * 512;
    u16* lB1 = sB + 2048 + w * 512;

    int aoff[4], boff[4];
#pragma unroll
    for (int m = 0; m < 4; m++) aoff[m] = (wr * 64 + m * 16 + l16) * 32 + lq * 8;
#pragma unroll
    for (int n = 0; n < 4; n++) boff[n] = (wc * 64 + n * 16 + l16) * 32 + lq * 8;

    const int nk = K >> 5;
    for (int kk = 0; kk < nk; ++kk) {
        __syncthreads();
        gload16(gA0, lA0);
        gload16(gA1, lA1);
        gload16(gB0, lB0);
        gload16(gB1, lB1);
        gA0 += 32; gA1 += 32; gB0 += 32; gB1 += 32;
        __syncthreads();
        bf16x8 af[4], bfr[4];
#pragma unroll
        for (int m = 0; m < 4; m++) af[m] = *(const bf16x8*)&sA[aoff[m]];
#pragma unroll
        for (int n = 0; n < 4; n++) bfr[n] = *(const bf16x8*)&sB[boff[n]];
        __builtin_amdgcn_s_setprio(1);
#pragma unroll
        for (int m = 0; m < 4; m++)
#pragma unroll
            for (int n = 0; n < 4; n++)
                acc[m][n] = __builtin_amdgcn_mfma_f32_16x16x32_bf16(af[m], bfr[n], acc[m][n], 0, 0, 0);
        __builtin_amdgcn_s_setprio(0);
    }

    const bool isrope = (tileN >= 1536);
#pragma unroll
    for (int n = 0; n < 4; n++) {
        int col = tileN + wc * 64 + n * 16 + l16;
        float bv = bcat[col];
#pragma unroll
        for (int m = 0; m < 4; m++) {
            int rowb = tileM + wr * 64 + m * 16 + (lq << 2);
#pragma unroll
            for (int r = 0; r < 4; r++) {
                float v = acc[m][n][r] + bv;
                if (!isrope) dcat[(size_t)(rowb + r) * 1536 + col] = v;
                else         krbuf[(size_t)(rowb + r) * 1024 + (col - 1536)] = f2bf(v);
            }
        }
    }
}

// ---------------- RMS norm (row-wise, strided in), fp32 in -> bf16 out --------
template <int C>
__global__ __launch_bounds__(256) void rmsnorm_bf16(
    const float* __restrict__ in, int istride, const float* __restrict__ wgt, u16* __restrict__ out)
{
    const int row = blockIdx.x;
    const int tid = threadIdx.x;
    constexpr int PER = C / 256;
    const float* p = in + (size_t)row * istride;
    float v[PER];
    float ss = 0.f;
#pragma unroll
    for (int i = 0; i < PER; i++) { v[i] = p[tid + i * 256]; ss += v[i] * v[i]; }
#pragma unroll
    for (int o = 32; o; o >>= 1) ss += __shfl_xor(ss, o, 64);
    __shared__ float red[4];
    if ((tid & 63) == 0) red[tid >> 6] = ss;
    __syncthreads();
    float tot = red[0] + red[1] + red[2] + red[3];
    float inv = rsqrtf(tot / (float)C + RMS_EPS);
    u16* q = out + (size_t)row * C;
#pragma unroll
    for (int i = 0; i < PER; i++) {
        int c = tid + i * 256;
        q[c] = f2bf(v[i] * inv * wgt[c]);
    }
}

// ---------------- V transpose: kvbuf[token][h*192+64+d] -> vT[(h*128+d)*4096+token]
__global__ __launch_bounds__(256) void transpose_v(
    const u16* __restrict__ kvbuf, u16* __restrict__ vT)
{
    __shared__ alignas(16) u16 tile[64][72];
    const int tid = threadIdx.x;
    const int t0 = blockIdx.x * 64;
    const int h = blockIdx.y >> 1, dh = blockIdx.y & 1;
    const int trow = tid >> 2, c8 = (tid & 3) * 8;
    const u16* src = kvbuf + (size_t)(t0 + trow) * 3072 + h * 192 + 64 + dh * 64 + c8;
    *(bf16x8*)&tile[trow][c8]      = *(const bf16x8*)src;
    *(bf16x8*)&tile[trow][c8 + 32] = *(const bf16x8*)(src + 32);
    __syncthreads();
    const int drow = tid >> 2, tc8 = (tid & 3) * 8;
    bf16x8 a, b2;
#pragma unroll
    for (int j = 0; j < 8; j++) {
        a[j]  = (short)tile[tc8 + j][drow];
        b2[j] = (short)tile[tc8 + 32 + j][drow];
    }
    u16* dst = vT + (size_t)(h * 128 + dh * 64 + drow) * MROWS + t0 + tc8;
    *(bf16x8*)dst = a;
    *(bf16x8*)(dst + 32) = b2;
}

// ---------------- causal flash attention ----------------
// QBLK=128 (4 waves x 32 q), KT=64. Pair p: q-tiles {p, 15-p} -> 34 k-tiles/block.
// grid (8,32) = 256 blocks, remapped so each XCD owns 4 bh (KV set fits its L2).
// Each K/V ds_read_b128 feeds TWO mfma (q-groups A,B) -> LDS bytes per q halved.
__global__ __launch_bounds__(256) void mla_attn(
    const u16* __restrict__ qbuf,   // (4096, 2048) head-major h*128
    const u16* __restrict__ kvbuf,  // (4096, 3072) per head 192: knope(64) v(128)
    const u16* __restrict__ krbuf,  // (4096, 1024) per head 64
    const u16* __restrict__ vT,     // (h*128+d, 4096 tokens)
    u16* __restrict__ obuf)         // (4096, 2048)
{
    const int flat = blockIdx.x + 8 * blockIdx.y;
    const int xcd = flat & 7, ii = flat >> 3;
    const int bh = xcd * 4 + (ii >> 3);      // 4 consecutive bh per XCD
    const int p  = ii & 7;
    const int b = bh >> 4, h = bh & 15;
    const int tid = threadIdx.x, lane = tid & 63, w = tid >> 6;
    const int l16 = lane & 15, lq = lane >> 4;

    __shared__ alignas(16) u16 sK[64 * 128];
    __shared__ alignas(16) u16 sVt[128 * 64];
    __shared__ alignas(16) u16 sP[8][16 * 64];   // [w*2+g][q16][k64], swizzled

    const int rowbase = b * Ss;
    const int sr = tid >> 2, sc = (tid & 3) * 32;   // K staging
    const int vd = tid >> 1, vh = (tid & 1) * 32;   // V staging
    const float C1 = 0.12751742f;    // softmax_scale * log2(e)
    const float THRR = 90.5f;        // defer-max threshold (~8 nats, raw units)

#pragma unroll 1
    for (int pass = 0; pass < 2; ++pass) {
        const int qt = pass ? (15 - p) : p;
        const int q0 = qt * 128;
        const int nkt = 2 * qt + 2;

        bf16x8 qf[2][4];
#pragma unroll
        for (int g = 0; g < 2; ++g) {
            const u16* qp = qbuf + (size_t)(rowbase + q0 + w * 32 + g * 16 + l16) * 2048 + h * 128 + lq * 8;
#pragma unroll
            for (int c = 0; c < 4; c++) qf[g][c] = *(const bf16x8*)(qp + c * 32);
        }
        float mi[2], li[2];
        f32x4 o[2][8];
#pragma unroll
        for (int g = 0; g < 2; ++g) {
            mi[g] = -3e38f; li[g] = 0.f;
#pragma unroll
            for (int d = 0; d < 8; d++)
#pragma unroll
                for (int r = 0; r < 4; r++) o[g][d][r] = 0.f;
        }

        bf16x8 kr[4], vr[4];
        {   // prologue: tile 0 -> regs
            const int krow = rowbase + sr;
            const u16* src = (sc < 64)
                ? kvbuf + (size_t)krow * 3072 + h * 192 + sc
                : krbuf + (size_t)krow * 1024 + h * 64 + (sc - 64);
#pragma unroll
            for (int j = 0; j < 4; j++) kr[j] = *(const bf16x8*)(src + j * 8);
            const u16* vsrc = vT + (size_t)(h * 128 + vd) * MROWS + rowbase + vh;
#pragma unroll
            for (int j = 0; j < 4; j++) vr[j] = *(const bf16x8*)(vsrc + j * 8);
        }

        for (int kt = 0; kt < nkt; ++kt) {
            __syncthreads();
#pragma unroll
            for (int j = 0; j < 4; j++) {
                int byteoff = sr * 256 + (sc + j * 8) * 2;
                *(bf16x8*)((char*)sK + (byteoff ^ ((sr & 7) << 4))) = kr[j];
            }
#pragma unroll
            for (int j = 0; j < 4; j++) {
                int byteoff = vd * 128 + (vh + j * 8) * 2;
                *(bf16x8*)((char*)sVt + (byteoff ^ ((vd & 7) << 4))) = vr[j];
            }
            __syncthreads();
            if (kt + 1 < nkt) {   // prefetch next tile into regs (hides under compute)
                const int krow = rowbase + (kt + 1) * 64 + sr;
                const u16* src = (sc < 64)
                    ? kvbuf + (size_t)krow * 3072 + h * 192 + sc
                    : krbuf + (size_t)krow * 1024 + h * 64 + (sc - 64);
#pragma unroll
                for (int j = 0; j < 4; j++) kr[j] = *(const bf16x8*)(src + j * 8);
                const u16* vsrc = vT + (size_t)(h * 128 + vd) * MROWS + rowbase + (kt + 1) * 64 + vh;
#pragma unroll
                for (int j = 0; j < 4; j++) vr[j] = *(const bf16x8*)(vsrc + j * 8);
            }

            // wave-dead skip (both q-groups share the same alive condition:
            // 64*kt - (q0+32w) is a multiple of 32, so <=15 iff <=31)
            const bool alive = (kt * 64) <= (q0 + w * 32 + 15);
            if (alive) {
                // QK^T swapped: A=K, B=Q -> D[k][q]; kf shared by both q-groups
                f32x4 scf[2][4];
#pragma unroll
                for (int g = 0; g < 2; ++g)
#pragma unroll
                    for (int n = 0; n < 4; n++)
#pragma unroll
                        for (int r = 0; r < 4; r++) scf[g][n][r] = 0.f;
                __builtin_amdgcn_s_setprio(1);
#pragma unroll
                for (int n = 0; n < 4; n++) {
#pragma unroll
                    for (int c = 0; c < 4; c++) {
                        int row = n * 16 + l16;
                        int byteoff = row * 256 + (c * 32 + lq * 8) * 2;
                        bf16x8 kf = *(const bf16x8*)((char*)sK + (byteoff ^ ((row & 7) << 4)));
                        scf[0][n] = __builtin_amdgcn_mfma_f32_16x16x32_bf16(kf, qf[0][c], scf[0][n], 0, 0, 0);
                        scf[1][n] = __builtin_amdgcn_mfma_f32_16x16x32_bf16(kf, qf[1][c], scf[1][n], 0, 0, 0);
                    }
                }
                __builtin_amdgcn_s_setprio(0);

                // online softmax per q-group; lane's q-row = l16
#pragma unroll
                for (int g = 0; g < 2; ++g) {
                    const int base = q0 + w * 32 + g * 16;
                    if (kt * 64 + 63 > base) {   // mask only diagonal-adjacent tiles
                        const int qg = base + l16;
#pragma unroll
                        for (int n = 0; n < 4; n++)
#pragma unroll
                            for (int r = 0; r < 4; r++) {
                                int kg = kt * 64 + n * 16 + lq * 4 + r;
                                if (kg > qg) scf[g][n][r] = -3e38f;
                            }
                    }
                    float mx = mi[g];
#pragma unroll
                    for (int n = 0; n < 4; n++)
#pragma unroll
                        for (int r = 0; r < 4; r++) mx = fmaxf(mx, scf[g][n][r]);
                    mx = fmaxf(mx, __shfl_xor(mx, 16, 64));
                    mx = fmaxf(mx, __shfl_xor(mx, 32, 64));
                    if (!__all(mx - mi[g] <= THRR)) {   // T13 defer-max
                        float f = exp2_fast((mi[g] - mx) * C1);
                        li[g] *= f;
#pragma unroll
                        for (int d = 0; d < 8; d++)
#pragma unroll
                            for (int r = 0; r < 4; r++) o[g][d][r] *= f;
                        mi[g] = mx;
                    }
                    float mc = mi[g] * C1;
                    float rs = 0.f;
#pragma unroll
                    for (int n = 0; n < 4; n++)
#pragma unroll
                        for (int r = 0; r < 4; r++) {
                            float pv = exp2_fast(__fmaf_rn(scf[g][n][r], C1, -mc));
                            scf[g][n][r] = pv;
                            rs += pv;
                        }
                    rs += __shfl_xor(rs, 16, 64);
                    rs += __shfl_xor(rs, 32, 64);
                    li[g] += rs;
                    // P -> wave-private LDS
                    char* pb = (char*)sP + ((w << 1) | g) * 2048;
#pragma unroll
                    for (int n = 0; n < 4; n++) {
                        ushort4 pk;
                        pk.x = f2bf(scf[g][n][0]); pk.y = f2bf(scf[g][n][1]);
                        pk.z = f2bf(scf[g][n][2]); pk.w = f2bf(scf[g][n][3]);
                        int byteoff = l16 * 128 + n * 32 + lq * 8;
                        *(ushort4*)(pb + (byteoff ^ ((l16 & 7) << 4))) = pk;
                    }
                }

                // PV swapped: A=V^T, B=P^T -> D[d][q]; vf shared by both q-groups
                __builtin_amdgcn_s_setprio(1);
#pragma unroll
                for (int c = 0; c < 2; c++) {
                    bf16x8 pf[2];
#pragma unroll
                    for (int g = 0; g < 2; ++g) {
                        char* pb = (char*)sP + ((w << 1) | g) * 2048;
                        int pbyte = l16 * 128 + (c * 32 + lq * 8) * 2;
                        pf[g] = *(const bf16x8*)(pb + (pbyte ^ ((l16 & 7) << 4)));
                    }
#pragma unroll
                    for (int d = 0; d < 8; d++) {
                        int vrow = d * 16 + l16;
                        int vbyte = vrow * 128 + (c * 32 + lq * 8) * 2;
                        bf16x8 vf = *(const bf16x8*)((char*)sVt + (vbyte ^ ((vrow & 7) << 4)));
                        o[0][d] = __builtin_amdgcn_mfma_f32_16x16x32_bf16(vf, pf[0], o[0][d], 0, 0, 0);
                        o[1][d] = __builtin_amdgcn_mfma_f32_16x16x32_bf16(vf, pf[1], o[1][d], 0, 0, 0);
                    }
                }
                __builtin_amdgcn_s_setprio(0);
            }
        }
        // epilogue: lane holds O^T[d][q=l16] per group
#pragma unroll
        for (int g = 0; g < 2; ++g) {
            float invl = 1.f / li[g];
            u16* op = obuf + (size_t)(rowbase + q0 + w * 32 + g * 16 + l16) * 2048 + h * 128;
#pragma unroll
            for (int d = 0; d < 8; d++) {
                ushort4 ok;
                ok.x = f2bf(o[g][d][0] * invl); ok.y = f2bf(o[g][d][1] * invl);
                ok.z = f2bf(o[g][d][2] * invl); ok.w = f2bf(o[g][d][3] * invl);
                *(ushort4*)(op + d * 16 + lq * 4) = ok;
            }
        }
    }
}

// ---------------- launch ----------------
extern "C" void kernel_launch(void* const* d_in, const int* in_sizes, int n_in,
                              void* d_out, int out_size, void* d_ws, size_t ws_size,
                              hipStream_t stream) {
    const float* x        = (const float*)d_in[0];
    const float* q_down_w = (const float*)d_in[1];
    const float* q_down_b = (const float*)d_in[2];
    const float* q_norm_w = (const float*)d_in[3];
    const float* q_up_w   = (const float*)d_in[4];
    const float* q_up_b   = (const float*)d_in[5];
    const float* kv_down_w= (const float*)d_in[6];
    const float* kv_down_b= (const float*)d_in[7];
    const float* kv_norm_w= (const float*)d_in[8];
    const float* kv_up_w  = (const float*)d_in[9];
    const float* kv_up_b  = (const float*)d_in[10];
    const float* k_rope_w = (const float*)d_in[11];
    const float* k_rope_b = (const float*)d_in[12];
    const float* out_w    = (const float*)d_in[13];
    const float* out_b    = (const float*)d_in[14];

    char* ws = (char*)d_ws;
    u16* xbf    = (u16*)(ws + 0);          // 16.78 MB ; later reused as vT
    u16* wcat   = (u16*)(ws + 16777216);   // 10.49 MB (2560x2048 bf16)
    u16* quw    = (u16*)(ws + 27262976);   // 4.19 MB
    u16* kvuw   = (u16*)(ws + 31457280);   // 3.15 MB
    u16* outw   = (u16*)(ws + 34603008);   // 8.39 MB
    float* bcat = (float*)(ws + 42991616); // 10 KB (pad to 16 KB)
    float* dcat = (float*)(ws + 43008000); // 25.17 MB (4096x1536 f32); reused as attnbuf
    u16* cq     = (u16*)(ws + 68173824);   // 8.39 MB
    u16* ckv    = (u16*)(ws + 76562432);   // 4.19 MB
    u16* qbuf   = (u16*)(ws + 80756736);   // 16.78 MB
    u16* kvbuf  = (u16*)(ws + 97533952);   // 25.17 MB
    u16* krbuf  = (u16*)(ws + 122699776);  // 8.39 MB  (end 131,088,384)
    u16* vT     = (u16*)(ws + 0);          // alias xbf (dead after gemm_down)
    u16* attnbuf= (u16*)(ws + 43008000);   // alias dcat (dead after rmsnorms)

    cvt_all<<<20992, 256, 0, stream>>>(
        x, xbf,
        q_down_w,  wcat,
        kv_down_w, wcat + 1024 * 2048,
        k_rope_w,  wcat + 1536 * 2048,
        q_up_w,    quw,
        kv_up_w,   kvuw,
        out_w,     outw);
    build_bcat<<<10, 256, 0, stream>>>(q_down_b, kv_down_b, k_rope_b, bcat);

    // fused down projections: x @ [q_down|kv_down|k_rope]^T
    gemm_down<<<dim3(20, 32), 256, 0, stream>>>(xbf, wcat, bcat, dcat, krbuf);
    rmsnorm_bf16<1024><<<MROWS, 256, 0, stream>>>(dcat, 1536, q_norm_w, cq);
    rmsnorm_bf16<512><<<MROWS, 256, 0, stream>>>(dcat + 1024, 1536, kv_norm_w, ckv);
    // up projections
    gemm_bt<u16><<<dim3(16, 32), 256, 0, stream>>>(cq, quw, q_up_b, qbuf, MROWS, 2048, 1024);
    gemm_bt<u16><<<dim3(24, 32), 256, 0, stream>>>(ckv, kvuw, kv_up_b, kvbuf, MROWS, 3072, 512);
    // V transpose (vT aliases xbf; xbf dead after gemm_down)
    transpose_v<<<dim3(64, 32), 256, 0, stream>>>(kvbuf, vT);
    // attention: QBLK=128, paired q-tiles, XCD-grouped bh
    mla_attn<<<dim3(8, 32), 256, 0, stream>>>(qbuf, kvbuf, krbuf, vT, attnbuf);
    // output projection
    gemm_bt<float><<<dim3(16, 32), 256, 0, stream>>>(attnbuf, outw, out_b, (float*)d_out, MROWS, 2048, 2048);
}